// Round 14
// baseline (97.500 us; speedup 1.0000x reference)
//
#include <hip/hip_runtime.h>

// RelativePositionalEncoding2D: out[b,i,j,e] = W[e, pos] + bias[e]
//   pos = clip(idxs[b,j] - idxs[b,i], -32, 32) + 32
// Shapes: B=1, S=1024, E=128, N=65. Output fp32 (1,S,S,E) = 512 MiB -> pure
// HBM-write-bound (floor ~80us at ~6.7 TB/s measured fill BW).
//
// R13 -> R14: block-uniform fast path. The fill kernel pipelines stores
// unboundedly because its data VGPRs are never rewritten (no WAR -> no vmcnt
// gating). Our loop's ds_read rewrites store-source regs every iter -> vmcnt
// waits on store drain. Fix: when a block's whole j-range is clipped to one
// side (min/max reduce over d; ~47% of blocks for near-monotone idxs), the
// block's entire 256 KiB is ONE row -> hoist to 4 VGPRs, store loop becomes
// register-source only (structurally identical to the fill kernel). Diagonal
// blocks keep the R13 path unchanged. Detection is general-correct.

#define MAXGAP 32
#define NIDX   65     // 2*MAXGAP+1
#define EDIM   128
#define E4     32     // EDIM/4 float4 per output row
#define PADE   132    // padded row stride in floats (528B, 16B-aligned)
#define CHUNKS 2      // half-rows per i
#define BLK    512    // threads per block; 32 waves/CU at 4 blocks/CU
#define NWAVE  (BLK / 64)

typedef float f32x4 __attribute__((ext_vector_type(4)));

__global__ __launch_bounds__(BLK) void relpos2d_kernel(
    const int* __restrict__ idxs,
    const float* __restrict__ W,       // (E, N) row-major
    const float* __restrict__ bias,    // (E,)
    f32x4* __restrict__ out,           // (S*S, E4)
    int S, int halfS)
{
    __shared__ float table[NIDX * PADE];  // 65*132*4 = 34,320 B
    __shared__ int   jidx[512];           // halfS entries
    __shared__ int   s_min[NWAVE], s_max[NWAVE];

    // table[p][e] = W[e*N + p] + bias[e]; read W coalesced, scatter to LDS.
    for (int t = threadIdx.x; t < NIDX * EDIM; t += BLK) {
        float w = W[t];              // coalesced: t = e*NIDX + p
        int e = t / NIDX;            // magic-mul (constant divisor)
        int p = t - e * NIDX;
        table[p * PADE + e] = w + bias[e];
    }

    const int i     = blockIdx.x >> 1;       // CHUNKS == 2
    const int chunk = blockIdx.x & (CHUNKS - 1);
    const int jbase = chunk * halfS;
    const int idx_i = idxs[i];

    // stage idxs slice + per-thread d-range over the values THIS thread wrote
    int dmin = 0x7fffffff, dmax = -0x7fffffff;
    for (int t = threadIdx.x; t < halfS; t += BLK) {
        int v = idxs[jbase + t];
        jidx[t] = v;
        int d = v - idx_i;
        dmin = dmin < d ? dmin : d;
        dmax = dmax > d ? dmax : d;
    }
    // wave reduce (64 lanes)
    #pragma unroll
    for (int off = 32; off > 0; off >>= 1) {
        int om = __shfl_xor(dmin, off, 64);
        int ox = __shfl_xor(dmax, off, 64);
        dmin = dmin < om ? dmin : om;
        dmax = dmax > ox ? dmax : ox;
    }
    const int wv = threadIdx.x >> 6;
    if ((threadIdx.x & 63) == 0) { s_min[wv] = dmin; s_max[wv] = dmax; }
    __syncthreads();

    int bmin = s_min[0], bmax = s_max[0];
    #pragma unroll
    for (int w = 1; w < NWAVE; ++w) {
        bmin = bmin < s_min[w] ? bmin : s_min[w];
        bmax = bmax > s_max[w] ? bmax : s_max[w];
    }

    const int lane4 = threadIdx.x & 31;   // float4 slot within the 512B row
    const int jsub  = threadIdx.x >> 5;   // 0..15: j within this step

    f32x4* __restrict__ orow = out + (size_t)i * S * E4 + (size_t)jbase * E4;

    if (bmin >= MAXGAP || bmax <= -MAXGAP) {
        // Entire block clips to one row: register-source store stream
        // (no LDS in loop, no WAR on store data -> fill-kernel issue behavior).
        const int p = (bmin >= MAXGAP) ? (NIDX - 1) : 0;
        const f32x4 v = reinterpret_cast<const f32x4*>(&table[p * PADE])[lane4];
        #pragma unroll 8
        for (int jj = 0; jj < halfS; jj += BLK / 32) {
            int j = jj + jsub;
            orow[(size_t)j * E4 + lane4] = v;
        }
    } else {
        // Diagonal-band block: proven R13 path.
        #pragma unroll 8
        for (int jj = 0; jj < halfS; jj += BLK / 32) {
            int j = jj + jsub;
            int d = jidx[j] - idx_i;                   // LDS broadcast read
            d = d < -MAXGAP ? -MAXGAP : (d > MAXGAP ? MAXGAP : d);
            int p = d + MAXGAP;

            f32x4 v = reinterpret_cast<const f32x4*>(&table[p * PADE])[lane4];
            orow[(size_t)j * E4 + lane4] = v;
        }
    }
}

extern "C" void kernel_launch(void* const* d_in, const int* in_sizes, int n_in,
                              void* d_out, int out_size, void* d_ws, size_t ws_size,
                              hipStream_t stream) {
    const int*   idxs = (const int*)  d_in[0];   // (B*S,) int32, B=1
    const float* W    = (const float*)d_in[1];   // (E, N) fp32
    const float* bias = (const float*)d_in[2];   // (E,)  fp32

    f32x4* out = (f32x4*)d_out;

    const int S     = in_sizes[0];   // B=1
    const int halfS = S / 2;
    const int grid  = S * CHUNKS;    // 2048 blocks: one (i, half-row) tile each

    relpos2d_kernel<<<grid, BLK, 0, stream>>>(idxs, W, bias, out, S, halfS);
}

// Round 15
// 95.656 us; speedup vs baseline: 1.0193x; 1.0193x over previous
//
#include <hip/hip_runtime.h>

// RelativePositionalEncoding2D: out[b,i,j,e] = W[e, pos] + bias[e]
//   pos = clip(idxs[b,j] - idxs[b,i], -32, 32) + 32
// Shapes: B=1, S=1024, E=128, N=65. Output fp32 (1,S,S,E) = 512 MiB -> pure
// HBM-write-bound.
//
// R14 -> R15: REVERT to R13 champion (95.51us, 5.62 TB/s, 70% peak).
// R14's null result (register-source store blocks == fill-kernel structure
// gained nothing) proves the store loop is at parity with pure-fill issue
// behavior; the residual vs fill's 6.7 TB/s rate is fixed ramp/prologue/tail
// overhead that doesn't amortize at 512 MiB. Exhausted axes with A/B
// evidence: nt(R6) prologue(R5) generations(R9) granularity(R10) dense
// window(R11) L1-table(R8) dep-break(R7) TLP(R12) ILP(R13) reg-source(R14).

#define MAXGAP 32
#define NIDX   65     // 2*MAXGAP+1
#define EDIM   128
#define E4     32     // EDIM/4 float4 per output row
#define PADE   132    // padded row stride in floats (528B, 16B-aligned)
#define CHUNKS 2      // half-rows per i
#define BLK    512    // threads per block; 32 waves/CU at 4 blocks/CU

typedef float f32x4 __attribute__((ext_vector_type(4)));

__global__ __launch_bounds__(BLK) void relpos2d_kernel(
    const int* __restrict__ idxs,
    const float* __restrict__ W,       // (E, N) row-major
    const float* __restrict__ bias,    // (E,)
    f32x4* __restrict__ out,           // (S*S, E4)
    int S, int halfS)
{
    __shared__ float table[NIDX * PADE];  // 65*132*4 = 34,320 B
    __shared__ int   jidx[512];           // halfS entries

    // table[p][e] = W[e*N + p] + bias[e]; read W coalesced, scatter to LDS.
    for (int t = threadIdx.x; t < NIDX * EDIM; t += BLK) {
        float w = W[t];              // coalesced: t = e*NIDX + p
        int e = t / NIDX;            // magic-mul (constant divisor)
        int p = t - e * NIDX;
        table[p * PADE + e] = w + bias[e];
    }

    const int i     = blockIdx.x >> 1;       // CHUNKS == 2
    const int chunk = blockIdx.x & (CHUNKS - 1);
    const int jbase = chunk * halfS;

    // stage this block's idxs[j] slice
    for (int t = threadIdx.x; t < halfS; t += BLK)
        jidx[t] = idxs[jbase + t];

    __syncthreads();

    const int lane4 = threadIdx.x & 31;   // float4 slot within the 512B row
    const int jsub  = threadIdx.x >> 5;   // 0..15: j within this step
    const int idx_i = idxs[i];

    f32x4* __restrict__ orow = out + (size_t)i * S * E4 + (size_t)jbase * E4;

    #pragma unroll 8
    for (int jj = 0; jj < halfS; jj += BLK / 32) {
        int j = jj + jsub;
        int d = jidx[j] - idx_i;                       // LDS broadcast read
        d = d < -MAXGAP ? -MAXGAP : (d > MAXGAP ? MAXGAP : d);
        int p = d + MAXGAP;

        f32x4 v = reinterpret_cast<const f32x4*>(&table[p * PADE])[lane4];
        orow[(size_t)j * E4 + lane4] = v;              // plain store
    }
}

extern "C" void kernel_launch(void* const* d_in, const int* in_sizes, int n_in,
                              void* d_out, int out_size, void* d_ws, size_t ws_size,
                              hipStream_t stream) {
    const int*   idxs = (const int*)  d_in[0];   // (B*S,) int32, B=1
    const float* W    = (const float*)d_in[1];   // (E, N) fp32
    const float* bias = (const float*)d_in[2];   // (E,)  fp32

    f32x4* out = (f32x4*)d_out;

    const int S     = in_sizes[0];   // B=1
    const int halfS = S / 2;
    const int grid  = S * CHUNKS;    // 2048 blocks: one (i, half-row) tile each

    relpos2d_kernel<<<grid, BLK, 0, stream>>>(idxs, W, bias, out, S, halfS);
}